// Round 1
// baseline (1088.810 us; speedup 1.0000x reference)
//
#include <hip/hip_runtime.h>
#include <math.h>

// ---------------------------------------------------------------------------
// Point Transformer block, MI355X. Round 0: correct fp32 implementation.
//   K0 knn_kernel   : exact 16-NN per point (matches jax.lax.top_k tie-break)
//   K1 top_proj     : top = bn(Wtop x);  phi/psi/alpha = W top + b  -> ws
//   K2 pt_attn      : fused d1/d2/g1/g2 + softmax + weighted sum -> yT in ws
//   K3 down_kernel  : out = bn(Wdown y) + x   (written [B][C][N] directly)
// ws usage: idx (1MB) + phi,psi,alpha,yT (4 x 8.39MB) ~= 35 MB.
// All GEMM stages: A in LDS [k][row] (stride 68, 2-way banks = free),
// weights transposed in LDS Wt[k][c ^ (k&0x7C)] (broadcast reads, conflict-free).
// ---------------------------------------------------------------------------

#define NPTS 4096
#define BATCH 4
#define CDIM 128
#define KNBR 16
#define SA 68           // row-stride (words) of [k][row] LDS operands

// ---- load 8 consecutive floats (c0 must be 16B aligned) ----
__device__ __forceinline__ void load8(const float* __restrict__ v, int c0, float (&o)[8]) {
    float4 a = *(const float4*)&v[c0];
    float4 b = *(const float4*)&v[c0 + 4];
    o[0]=a.x; o[1]=a.y; o[2]=a.z; o[3]=a.w; o[4]=b.x; o[5]=b.y; o[6]=b.z; o[7]=b.w;
}

// ---- stage 128x128 row-major W[c][k] into LDS as Wt[k][c ^ (k&0x7C)] ----
// coalesced global b128 reads, 4x4 in-register transpose, ~4-way LDS write conflicts
__device__ __forceinline__ void stage_wt(const float* __restrict__ gW, float* __restrict__ sW, int t) {
    const int kq = t & 31;          // k-quad
    const int cq0 = t >> 5;         // 0..7
    #pragma unroll
    for (int r = 0; r < 4; ++r) {
        const int c0 = (cq0 + r * 8) * 4;
        const int k0 = kq * 4;
        float4 w0 = *(const float4*)&gW[(c0+0)*128 + k0];
        float4 w1 = *(const float4*)&gW[(c0+1)*128 + k0];
        float4 w2 = *(const float4*)&gW[(c0+2)*128 + k0];
        float4 w3 = *(const float4*)&gW[(c0+3)*128 + k0];
        const float r0[4] = {w0.x,w0.y,w0.z,w0.w};
        const float r1[4] = {w1.x,w1.y,w1.z,w1.w};
        const float r2[4] = {w2.x,w2.y,w2.z,w2.w};
        const float r3[4] = {w3.x,w3.y,w3.z,w3.w};
        #pragma unroll
        for (int j = 0; j < 4; ++j) {
            const int k = k0 + j;
            float4 v = make_float4(r0[j], r1[j], r2[j], r3[j]);
            *(float4*)&sW[k*128 + (c0 ^ (k & 0x7C))] = v;
        }
    }
}

// ---- GEMM micro-kernel: acc[i][j] += sum_k A[k][r0+i] * W[c0+j][k] ----
__device__ __forceinline__ void gemm128(const float* __restrict__ sIn, const float* __restrict__ sW,
                                        int r0, int c0, float (&acc)[4][8]) {
    #pragma unroll 4
    for (int k = 0; k < 128; ++k) {
        float4 a = *(const float4*)&sIn[k*SA + r0];
        const int sw = k & 0x7C;
        float4 b0 = *(const float4*)&sW[k*128 + (c0 ^ sw)];
        float4 b1 = *(const float4*)&sW[k*128 + ((c0+4) ^ sw)];
        const float av[4] = {a.x, a.y, a.z, a.w};
        const float bv[8] = {b0.x,b0.y,b0.z,b0.w,b1.x,b1.y,b1.z,b1.w};
        #pragma unroll
        for (int i = 0; i < 4; ++i)
            #pragma unroll
            for (int j = 0; j < 8; ++j)
                acc[i][j] = fmaf(av[i], bv[j], acc[i][j]);
    }
}

// ---- write register tile to LDS in [c][row] layout (b128 along rows) ----
__device__ __forceinline__ void write_colmajor(float* __restrict__ sDst, int r0, int c0,
                                               const float (&v)[4][8]) {
    #pragma unroll
    for (int j = 0; j < 8; ++j) {
        float4 q = make_float4(v[0][j], v[1][j], v[2][j], v[3][j]);
        *(float4*)&sDst[(c0 + j)*SA + r0] = q;
    }
}

// ---- epilogues ----
template<bool RELU>
__device__ __forceinline__ void epi_bn(float (&acc)[4][8], const float* __restrict__ bias,
                                       const float* __restrict__ sc, const float* __restrict__ sh, int c0) {
    float bb[8], ss[8], tt[8];
    load8(bias, c0, bb); load8(sc, c0, ss); load8(sh, c0, tt);
    #pragma unroll
    for (int i = 0; i < 4; ++i)
        #pragma unroll
        for (int j = 0; j < 8; ++j) {
            float v = fmaf(acc[i][j] + bb[j], ss[j], tt[j]);
            if (RELU) v = fmaxf(v, 0.f);
            acc[i][j] = v;
        }
}

__device__ __forceinline__ void epi_bias(float (&acc)[4][8], const float* __restrict__ bias, int c0) {
    float bb[8]; load8(bias, c0, bb);
    #pragma unroll
    for (int i = 0; i < 4; ++i)
        #pragma unroll
        for (int j = 0; j < 8; ++j) acc[i][j] += bb[j];
}

__device__ __forceinline__ void store_rows(float* __restrict__ dst, int b, int n0, int r0, int c0,
                                           const float (&v)[4][8]) {
    #pragma unroll
    for (int i = 0; i < 4; ++i) {
        float* row = &dst[((size_t)b*NPTS + n0 + r0 + i)*CDIM + c0];
        *(float4*)row     = make_float4(v[i][0], v[i][1], v[i][2], v[i][3]);
        *(float4*)(row+4) = make_float4(v[i][4], v[i][5], v[i][6], v[i][7]);
    }
}

// ===========================================================================
// K0: exact KNN.  Block = 512 thr (8 waves) = 64 queries; wave w scans
// candidate chunk [w*512,(w+1)*512); per-lane sorted top-16 (lexicographic
// (d2, idx) to match top_k tie-breaking); bitonic min-ladder merge of 8 lists.
// ===========================================================================
__global__ __launch_bounds__(512)
void knn_kernel(const float* __restrict__ p, int* __restrict__ idx_out) {
    __shared__ float4 p4[NPTS];           // 64 KB: x,y,z,|p|^2
    __shared__ float  mv[8*16*64];        // 32 KB partial vals [w][j][q]
    __shared__ int    mi[8*16*64];        // 32 KB partial idx
    const int b = blockIdx.y, n0 = blockIdx.x*64, t = threadIdx.x;
    const float* pb = p + (size_t)b*3*NPTS;
    for (int m = t; m < NPTS; m += 512) {
        float xx = pb[m], yy = pb[NPTS+m], zz = pb[2*NPTS+m];
        p4[m] = make_float4(xx, yy, zz, xx*xx + yy*yy + zz*zz);
    }
    __syncthreads();
    const int w = t >> 6, l = t & 63;
    const float4 Q = p4[n0 + l];
    float bv[16]; int bi[16];
    #pragma unroll
    for (int j = 0; j < 16; ++j) { bv[j] = __builtin_inff(); bi[j] = 0x7FFFFFFF; }
    const int m0 = w * 512;
    for (int mm = 0; mm < 512; ++mm) {
        const int m = m0 + mm;
        const float4 P = p4[m];
        float dot = Q.x * P.x;
        dot = fmaf(Q.y, P.y, dot);
        dot = fmaf(Q.z, P.z, dot);
        const float d2 = fmaf(-2.f, dot, Q.w + P.w);
        if (d2 < bv[15]) {                       // strict: ties keep earlier idx
            float cv = d2; int ci = m;
            #pragma unroll
            for (int j = 0; j < 16; ++j) {       // branch-free sorted insert
                bool s_ = (cv < bv[j]) || (cv == bv[j] && ci < bi[j]);
                float tv = bv[j]; int ti = bi[j];
                bv[j] = s_ ? cv : tv;  bi[j] = s_ ? ci : ti;
                cv    = s_ ? tv : cv;  ci    = s_ ? ti : ci;
            }
        }
    }
    #pragma unroll
    for (int j = 0; j < 16; ++j) { mv[(w*16+j)*64 + l] = bv[j]; mi[(w*16+j)*64 + l] = bi[j]; }
    __syncthreads();
    if (t < 64) {                                // wave 0: lane q merges 8 lists
        const int q = t;
        float av[16]; int ai[16];
        #pragma unroll
        for (int j = 0; j < 16; ++j) { av[j] = mv[j*64+q]; ai[j] = mi[j*64+q]; }
        for (int w2 = 1; w2 < 8; ++w2) {
            float bw[16]; int bidx[16];
            #pragma unroll
            for (int j = 0; j < 16; ++j) { bw[j] = mv[(w2*16+j)*64+q]; bidx[j] = mi[(w2*16+j)*64+q]; }
            float cv[16]; int ci[16];
            #pragma unroll
            for (int j = 0; j < 16; ++j) {       // min-ladder -> bitonic top-16
                float a1 = av[j]; int a2 = ai[j];
                float b1 = bw[15-j]; int b2 = bidx[15-j];
                bool lt = (a1 < b1) || (a1 == b1 && a2 < b2);
                cv[j] = lt ? a1 : b1; ci[j] = lt ? a2 : b2;
            }
            #pragma unroll
            for (int gap = 8; gap >= 1; gap >>= 1) {   // bitonic merge (asc)
                #pragma unroll
                for (int i = 0; i < 16; ++i) {
                    if ((i & gap) == 0) {
                        const int k2 = i + gap;
                        bool le = (cv[i] < cv[k2]) || (cv[i] == cv[k2] && ci[i] < ci[k2]);
                        float tv = cv[i], tw = cv[k2]; int ti = ci[i], tj = ci[k2];
                        cv[i]  = le ? tv : tw; ci[i]  = le ? ti : tj;
                        cv[k2] = le ? tw : tv; ci[k2] = le ? tj : ti;
                    }
                }
            }
            #pragma unroll
            for (int j = 0; j < 16; ++j) { av[j] = cv[j]; ai[j] = ci[j]; }
        }
        int* orow = &idx_out[((size_t)b*NPTS + n0 + q)*KNBR];
        #pragma unroll
        for (int j = 0; j < 16; ++j) orow[j] = ai[j];
    }
}

// ===========================================================================
// K1: top = bn(Wtop x + b); phi/psi/alpha = W top + b  -> ws [B][N][C]
// Block = 256 thr, 64 points.
// ===========================================================================
__global__ __launch_bounds__(256)
void top_proj_kernel(const float* __restrict__ x,
                     const float* __restrict__ Wt_, const float* __restrict__ bt_,
                     const float* __restrict__ st_, const float* __restrict__ tt_,
                     const float* __restrict__ Wph, const float* __restrict__ bph,
                     const float* __restrict__ Wps, const float* __restrict__ bps,
                     const float* __restrict__ Wal, const float* __restrict__ bal,
                     float* __restrict__ phi, float* __restrict__ psi, float* __restrict__ alp) {
    __shared__ float sX[128*SA];
    __shared__ float sT[128*SA];
    __shared__ float sW[128*128];
    const int t = threadIdx.x, tx = t & 15, ty = t >> 4;
    const int r0 = tx*4, c0 = ty*8;
    const int b = blockIdx.y, n0 = blockIdx.x*64;
    #pragma unroll
    for (int rr = 0; rr < 8; ++rr) {          // x [B][C][N] stages directly as [k][n]
        const int k = rr*16 + ty;
        *(float4*)&sX[k*SA + r0] = *(const float4*)&x[((size_t)b*CDIM + k)*NPTS + n0 + r0];
    }
    stage_wt(Wt_, sW, t);
    __syncthreads();
    {
        float acc[4][8] = {};
        gemm128(sX, sW, r0, c0, acc);
        epi_bn<false>(acc, bt_, st_, tt_, c0);
        write_colmajor(sT, r0, c0, acc);
    }
    __syncthreads();
    stage_wt(Wph, sW, t); __syncthreads();
    { float a2[4][8] = {}; gemm128(sT, sW, r0, c0, a2); epi_bias(a2, bph, c0); store_rows(phi, b, n0, r0, c0, a2); }
    __syncthreads();
    stage_wt(Wps, sW, t); __syncthreads();
    { float a2[4][8] = {}; gemm128(sT, sW, r0, c0, a2); epi_bias(a2, bps, c0); store_rows(psi, b, n0, r0, c0, a2); }
    __syncthreads();
    stage_wt(Wal, sW, t); __syncthreads();
    { float a2[4][8] = {}; gemm128(sT, sW, r0, c0, a2); epi_bias(a2, bal, c0); store_rows(alp, b, n0, r0, c0, a2); }
}

// ===========================================================================
// K2: fused per-neighbor MLP chain + softmax + weighted sum.
// Block = 256 thr, 4 points x 16 neighbors = 64 rows. Softmax over k is a
// 4-lane shfl_xor reduce (thread rows tx*4+i; lanes tx^1, tx^2 = same point).
// ===========================================================================
__global__ __launch_bounds__(256)
void pt_attn_kernel(const float* __restrict__ p,
                    const float* __restrict__ phi, const float* __restrict__ psi,
                    const float* __restrict__ alp, const int* __restrict__ idx,
                    const float* __restrict__ W_d1, const float* __restrict__ b_d1,
                    const float* __restrict__ W_d2, const float* __restrict__ b_d2,
                    const float* __restrict__ W_g1, const float* __restrict__ b_g1,
                    const float* __restrict__ W_g2, const float* __restrict__ b_g2,
                    const float* __restrict__ s_d1, const float* __restrict__ t_d1,
                    const float* __restrict__ s_d2, const float* __restrict__ t_d2,
                    const float* __restrict__ s_g1, const float* __restrict__ t_g1,
                    const float* __restrict__ s_g2, const float* __restrict__ t_g2,
                    float* __restrict__ yT) {
    __shared__ float sA[128*SA];
    __shared__ float sB[128*SA];
    __shared__ float sW[128*128];
    __shared__ float sWd1[3*128];
    __shared__ float sRel[3*SA];
    __shared__ float sPhi[4*132];
    __shared__ int   sIdx[64];
    const int t = threadIdx.x, tx = t & 15, ty = t >> 4;
    const int r0 = tx*4, c0 = ty*8;
    const int b = blockIdx.y, n0 = blockIdx.x*4;

    // -- P1: small staging --
    if (t < 64) sIdx[t] = idx[((size_t)b*NPTS + n0 + (t >> 4))*KNBR + (t & 15)];
    if (t < 128) {
        const int pt_ = t >> 5, cq = t & 31;
        *(float4*)&sPhi[pt_*132 + cq*4] = *(const float4*)&phi[((size_t)b*NPTS + n0 + pt_)*CDIM + cq*4];
    }
    if (t >= 128) {                          // Wd1t[j][c], plain layout
        const int c = t - 128;
        #pragma unroll
        for (int j = 0; j < 3; ++j) sWd1[j*128 + c] = W_d1[c*3 + j];
    }
    __syncthreads();
    // -- P1b: rel + stage Wd2 --
    if (t < 192) {
        const int j = t / 64, r = t % 64;
        const float pq = p[((size_t)b*3 + j)*NPTS + n0 + (r >> 4)];
        const float pn = p[((size_t)b*3 + j)*NPTS + sIdx[r]];
        sRel[j*SA + r] = pq - pn;
    }
    stage_wt(W_d2, sW, t);
    __syncthreads();
    // -- S2: h = relu(bn_d1(Wd1 rel + b)) -> sA --
    {
        float acc[4][8] = {};
        #pragma unroll
        for (int k = 0; k < 3; ++k) {
            float4 a = *(const float4*)&sRel[k*SA + r0];
            float bv8[8]; load8(&sWd1[k*128], c0, bv8);
            const float av[4] = {a.x, a.y, a.z, a.w};
            #pragma unroll
            for (int i = 0; i < 4; ++i)
                #pragma unroll
                for (int j = 0; j < 8; ++j) acc[i][j] = fmaf(av[i], bv8[j], acc[i][j]);
        }
        epi_bn<true>(acc, b_d1, s_d1, t_d1, c0);
        write_colmajor(sA, r0, c0, acc);
    }
    __syncthreads();
    // -- S3: delta = bn_d2(Wd2 h + b) -> registers (persist to the end) --
    float dl[4][8];
    {
        float acc[4][8] = {};
        gemm128(sA, sW, r0, c0, acc);
        epi_bn<false>(acc, b_d2, s_d2, t_d2, c0);
        #pragma unroll
        for (int i = 0; i < 4; ++i)
            #pragma unroll
            for (int j = 0; j < 8; ++j) dl[i][j] = acc[i][j];
    }
    __syncthreads();
    // -- P4: g0 = phi - psi_n + delta -> sA ; stage Wg1 --
    {
        const int pt_ = tx >> 2;
        float ph[8]; load8(&sPhi[pt_*132], c0, ph);
        float g0[4][8];
        #pragma unroll
        for (int i = 0; i < 4; ++i) {
            const int jn = sIdx[r0 + i];
            float ps[8]; load8(&psi[((size_t)b*NPTS + jn)*CDIM], c0, ps);
            #pragma unroll
            for (int j = 0; j < 8; ++j) g0[i][j] = ph[j] - ps[j] + dl[i][j];
        }
        write_colmajor(sA, r0, c0, g0);
        stage_wt(W_g1, sW, t);
    }
    __syncthreads();
    // -- S5: g1 = relu(bn_g1(...)) -> sB --
    {
        float acc[4][8] = {};
        gemm128(sA, sW, r0, c0, acc);
        epi_bn<true>(acc, b_g1, s_g1, t_g1, c0);
        write_colmajor(sB, r0, c0, acc);
    }
    __syncthreads();
    stage_wt(W_g2, sW, t);
    __syncthreads();
    // -- S6: g2 = bn_g2(...) -> registers --
    float g2[4][8] = {};
    gemm128(sB, sW, r0, c0, g2);
    epi_bn<false>(g2, b_g2, s_g2, t_g2, c0);
    // -- softmax over the 16 neighbors (4 rows in-thread x lanes tx^1, tx^2) --
    float den[8];
    #pragma unroll
    for (int j = 0; j < 8; ++j) {
        float m_ = fmaxf(fmaxf(g2[0][j], g2[1][j]), fmaxf(g2[2][j], g2[3][j]));
        m_ = fmaxf(m_, __shfl_xor(m_, 1));
        m_ = fmaxf(m_, __shfl_xor(m_, 2));
        float s_ = 0.f;
        #pragma unroll
        for (int i = 0; i < 4; ++i) { g2[i][j] = __expf(g2[i][j] - m_); s_ += g2[i][j]; }
        s_ += __shfl_xor(s_, 1);
        s_ += __shfl_xor(s_, 2);
        den[j] = s_;
    }
    // -- y = sum_k attn * (alpha_n + delta) --
    float ya[8] = {};
    #pragma unroll
    for (int i = 0; i < 4; ++i) {
        const int jn = sIdx[r0 + i];
        float al[8]; load8(&alp[((size_t)b*NPTS + jn)*CDIM], c0, al);
        #pragma unroll
        for (int j = 0; j < 8; ++j) ya[j] = fmaf(g2[i][j], al[j] + dl[i][j], ya[j]);
    }
    #pragma unroll
    for (int j = 0; j < 8; ++j) {
        ya[j] += __shfl_xor(ya[j], 1);
        ya[j] += __shfl_xor(ya[j], 2);
    }
    if ((tx & 3) == 0) {
        const int pt_ = tx >> 2;
        #pragma unroll
        for (int j = 0; j < 8; ++j)
            yT[((size_t)b*CDIM + c0 + j)*NPTS + n0 + pt_] = ya[j] / den[j];
    }
}

// ===========================================================================
// K3: out = bn_down(Wdown y + b) + x, written [B][C][N] (coalesced both sides)
// ===========================================================================
__global__ __launch_bounds__(256)
void down_kernel(const float* __restrict__ yT, const float* __restrict__ x,
                 const float* __restrict__ Wd, const float* __restrict__ bd,
                 const float* __restrict__ sd, const float* __restrict__ td,
                 float* __restrict__ out) {
    __shared__ float sY[128*SA];
    __shared__ float sW[128*128];
    const int t = threadIdx.x, tx = t & 15, ty = t >> 4;
    const int r0 = tx*4, c0 = ty*8;
    const int b = blockIdx.y, n0 = blockIdx.x*64;
    #pragma unroll
    for (int rr = 0; rr < 8; ++rr) {
        const int k = rr*16 + ty;
        *(float4*)&sY[k*SA + r0] = *(const float4*)&yT[((size_t)b*CDIM + k)*NPTS + n0 + r0];
    }
    stage_wt(Wd, sW, t);
    __syncthreads();
    float acc[4][8] = {};
    gemm128(sY, sW, r0, c0, acc);
    epi_bn<false>(acc, bd, sd, td, c0);
    #pragma unroll
    for (int j = 0; j < 8; ++j) {
        const float* xrow = &x[((size_t)b*CDIM + c0 + j)*NPTS + n0 + r0];
        float4 res = *(const float4*)xrow;
        float4 o = make_float4(acc[0][j] + res.x, acc[1][j] + res.y,
                               acc[2][j] + res.z, acc[3][j] + res.w);
        *(float4*)&out[((size_t)b*CDIM + c0 + j)*NPTS + n0 + r0] = o;
    }
}

// ===========================================================================
extern "C" void kernel_launch(void* const* d_in, const int* in_sizes, int n_in,
                              void* d_out, int out_size, void* d_ws, size_t ws_size,
                              hipStream_t stream) {
    const float* p    = (const float*)d_in[0];
    const float* x    = (const float*)d_in[1];
    const float* Wtop = (const float*)d_in[2];  const float* btop = (const float*)d_in[3];
    const float* Wphi = (const float*)d_in[4];  const float* bphi = (const float*)d_in[5];
    const float* Wpsi = (const float*)d_in[6];  const float* bpsi = (const float*)d_in[7];
    const float* Walp = (const float*)d_in[8];  const float* balp = (const float*)d_in[9];
    const float* Wd1  = (const float*)d_in[10]; const float* bd1  = (const float*)d_in[11];
    const float* Wd2  = (const float*)d_in[12]; const float* bd2  = (const float*)d_in[13];
    const float* Wg1  = (const float*)d_in[14]; const float* bg1  = (const float*)d_in[15];
    const float* Wg2  = (const float*)d_in[16]; const float* bg2  = (const float*)d_in[17];
    const float* Wdn  = (const float*)d_in[18]; const float* bdn  = (const float*)d_in[19];
    const float* stop = (const float*)d_in[20]; const float* ttop = (const float*)d_in[21];
    const float* sd1  = (const float*)d_in[22]; const float* td1  = (const float*)d_in[23];
    const float* sd2  = (const float*)d_in[24]; const float* td2  = (const float*)d_in[25];
    const float* sg1  = (const float*)d_in[26]; const float* tg1  = (const float*)d_in[27];
    const float* sg2  = (const float*)d_in[28]; const float* tg2  = (const float*)d_in[29];
    const float* sdn  = (const float*)d_in[30]; const float* tdn  = (const float*)d_in[31];

    char* ws = (char*)d_ws;
    int*   idx = (int*)ws;                                   // 1 MB
    float* phi = (float*)(ws + (1 << 20));
    float* psi = phi + (size_t)BATCH*NPTS*CDIM;
    float* alp = psi + (size_t)BATCH*NPTS*CDIM;
    float* yT  = alp + (size_t)BATCH*NPTS*CDIM;

    dim3 gk(NPTS/64, BATCH);
    knn_kernel<<<gk, 512, 0, stream>>>(p, idx);
    dim3 g1(NPTS/64, BATCH);
    top_proj_kernel<<<g1, 256, 0, stream>>>(x, Wtop, btop, stop, ttop,
                                            Wphi, bphi, Wpsi, bpsi, Walp, balp,
                                            phi, psi, alp);
    dim3 g2(NPTS/4, BATCH);
    pt_attn_kernel<<<g2, 256, 0, stream>>>(p, phi, psi, alp, idx,
                                           Wd1, bd1, Wd2, bd2, Wg1, bg1, Wg2, bg2,
                                           sd1, td1, sd2, td2, sg1, tg1, sg2, tg2, yT);
    dim3 g3(NPTS/64, BATCH);
    down_kernel<<<g3, 256, 0, stream>>>(yT, x, Wdn, bdn, sdn, tdn, (float*)d_out);
}

// Round 5
// 1006.140 us; speedup vs baseline: 1.0822x; 1.0822x over previous
//
#include <hip/hip_runtime.h>
#include <math.h>

// ---------------------------------------------------------------------------
// Point Transformer block, MI355X. Round 1 (resubmit x3): occupancy fix.
//  - pt_attn/top_proj/down: single activation buffer (ping-pong via barriers)
//    + K-split weight staging (sW = 64x128 fp32 = 32 KB) => ~71 KB LDS
//    => 2 blocks/CU (was 1), 8 waves/CU.  Bit-exact same math as round 0.
//  - knn: tie-break compare removed from insert ladder (provably redundant).
// ---------------------------------------------------------------------------

#define NPTS 4096
#define BATCH 4
#define CDIM 128
#define KNBR 16
#define SA 68           // row-stride (words) of [k][row] LDS operands

__device__ __forceinline__ void load8(const float* __restrict__ v, int c0, float (&o)[8]) {
    float4 a = *(const float4*)&v[c0];
    float4 b = *(const float4*)&v[c0 + 4];
    o[0]=a.x; o[1]=a.y; o[2]=a.z; o[3]=a.w; o[4]=b.x; o[5]=b.y; o[6]=b.z; o[7]=b.w;
}

// ---- stage HALF of 128x128 row-major W[c][k] (k in [k0,k0+64)) into LDS as
//      Wt[kl][c ^ (kl&0x7C)], kl = k - k0.  8 float4 loads + 8 writes/thread.
__device__ __forceinline__ void stage_wt_half(const float* __restrict__ gW, float* __restrict__ sW,
                                              int t, int k0) {
    const int kq = t & 15;          // k-quad within half (16 quads)
    const int cg = t >> 4;          // 0..15
    #pragma unroll
    for (int r = 0; r < 2; ++r) {
        const int c0 = (cg + r * 16) * 4;
        const int kk = kq * 4;      // local k base
        float4 w0 = *(const float4*)&gW[(c0+0)*128 + k0 + kk];
        float4 w1 = *(const float4*)&gW[(c0+1)*128 + k0 + kk];
        float4 w2 = *(const float4*)&gW[(c0+2)*128 + k0 + kk];
        float4 w3 = *(const float4*)&gW[(c0+3)*128 + k0 + kk];
        const float r0v[4] = {w0.x,w0.y,w0.z,w0.w};
        const float r1v[4] = {w1.x,w1.y,w1.z,w1.w};
        const float r2v[4] = {w2.x,w2.y,w2.z,w2.w};
        const float r3v[4] = {w3.x,w3.y,w3.z,w3.w};
        #pragma unroll
        for (int j = 0; j < 4; ++j) {
            const int kl = kk + j;
            float4 v = make_float4(r0v[j], r1v[j], r2v[j], r3v[j]);
            *(float4*)&sW[kl*128 + (c0 ^ (kl & 0x7C))] = v;
        }
    }
}

// ---- GEMM over 64 k's: acc[i][j] += sum_kl A[kl][r0+i] * Wt[kl][c0+j] ----
__device__ __forceinline__ void gemm64(const float* __restrict__ sIn, const float* __restrict__ sW,
                                       int r0, int c0, float (&acc)[4][8]) {
    #pragma unroll 4
    for (int kl = 0; kl < 64; ++kl) {
        float4 a = *(const float4*)&sIn[kl*SA + r0];
        const int sw = kl & 0x7C;
        float4 b0 = *(const float4*)&sW[kl*128 + (c0 ^ sw)];
        float4 b1 = *(const float4*)&sW[kl*128 + ((c0+4) ^ sw)];
        const float av[4] = {a.x, a.y, a.z, a.w};
        const float bv[8] = {b0.x,b0.y,b0.z,b0.w,b1.x,b1.y,b1.z,b1.w};
        #pragma unroll
        for (int i = 0; i < 4; ++i)
            #pragma unroll
            for (int j = 0; j < 8; ++j)
                acc[i][j] = fmaf(av[i], bv[j], acc[i][j]);
    }
}

__device__ __forceinline__ void write_colmajor(float* __restrict__ sDst, int r0, int c0,
                                               const float (&v)[4][8]) {
    #pragma unroll
    for (int j = 0; j < 8; ++j) {
        float4 q = make_float4(v[0][j], v[1][j], v[2][j], v[3][j]);
        *(float4*)&sDst[(c0 + j)*SA + r0] = q;
    }
}

template<bool RELU>
__device__ __forceinline__ void epi_bn(float (&acc)[4][8], const float* __restrict__ bias,
                                       const float* __restrict__ sc, const float* __restrict__ sh, int c0) {
    float bb[8], ss[8], tt[8];
    load8(bias, c0, bb); load8(sc, c0, ss); load8(sh, c0, tt);
    #pragma unroll
    for (int i = 0; i < 4; ++i)
        #pragma unroll
        for (int j = 0; j < 8; ++j) {
            float v = fmaf(acc[i][j] + bb[j], ss[j], tt[j]);
            if (RELU) v = fmaxf(v, 0.f);
            acc[i][j] = v;
        }
}

__device__ __forceinline__ void epi_bias(float (&acc)[4][8], const float* __restrict__ bias, int c0) {
    float bb[8]; load8(bias, c0, bb);
    #pragma unroll
    for (int i = 0; i < 4; ++i)
        #pragma unroll
        for (int j = 0; j < 8; ++j) acc[i][j] += bb[j];
}

__device__ __forceinline__ void store_rows(float* __restrict__ dst, int b, int n0, int r0, int c0,
                                           const float (&v)[4][8]) {
    #pragma unroll
    for (int i = 0; i < 4; ++i) {
        float* row = &dst[((size_t)b*NPTS + n0 + r0 + i)*CDIM + c0];
        *(float4*)row     = make_float4(v[i][0], v[i][1], v[i][2], v[i][3]);
        *(float4*)(row+4) = make_float4(v[i][4], v[i][5], v[i][6], v[i][7]);
    }
}

// ===========================================================================
// K0: exact KNN.
// ===========================================================================
__global__ __launch_bounds__(512)
void knn_kernel(const float* __restrict__ p, int* __restrict__ idx_out) {
    __shared__ float4 p4[NPTS];
    __shared__ float  mv[8*16*64];
    __shared__ int    mi[8*16*64];
    const int b = blockIdx.y, n0 = blockIdx.x*64, t = threadIdx.x;
    const float* pb = p + (size_t)b*3*NPTS;
    for (int m = t; m < NPTS; m += 512) {
        float xx = pb[m], yy = pb[NPTS+m], zz = pb[2*NPTS+m];
        p4[m] = make_float4(xx, yy, zz, xx*xx + yy*yy + zz*zz);
    }
    __syncthreads();
    const int w = t >> 6, l = t & 63;
    const float4 Q = p4[n0 + l];
    float bv[16]; int bi[16];
    #pragma unroll
    for (int j = 0; j < 16; ++j) { bv[j] = __builtin_inff(); bi[j] = 0x7FFFFFFF; }
    const int m0 = w * 512;
    for (int mm = 0; mm < 512; ++mm) {
        const int m = m0 + mm;
        const float4 P = p4[m];
        float dot = Q.x * P.x;
        dot = fmaf(Q.y, P.y, dot);
        dot = fmaf(Q.z, P.z, dot);
        const float d2 = fmaf(-2.f, dot, Q.w + P.w);
        if (d2 < bv[15]) {
            float cv = d2; int ci = m;
            #pragma unroll
            for (int j = 0; j < 16; ++j) {       // strict-<: keeps (d2,idx) order
                bool s_ = (cv < bv[j]);
                float tv = bv[j]; int ti = bi[j];
                bv[j] = s_ ? cv : tv;  bi[j] = s_ ? ci : ti;
                cv    = s_ ? tv : cv;  ci    = s_ ? ti : ci;
            }
        }
    }
    #pragma unroll
    for (int j = 0; j < 16; ++j) { mv[(w*16+j)*64 + l] = bv[j]; mi[(w*16+j)*64 + l] = bi[j]; }
    __syncthreads();
    if (t < 64) {
        const int q = t;
        float av[16]; int ai[16];
        #pragma unroll
        for (int j = 0; j < 16; ++j) { av[j] = mv[j*64+q]; ai[j] = mi[j*64+q]; }
        for (int w2 = 1; w2 < 8; ++w2) {
            float bw[16]; int bidx[16];
            #pragma unroll
            for (int j = 0; j < 16; ++j) { bw[j] = mv[(w2*16+j)*64+q]; bidx[j] = mi[(w2*16+j)*64+q]; }
            float cv[16]; int ci[16];
            #pragma unroll
            for (int j = 0; j < 16; ++j) {
                float a1 = av[j]; int a2 = ai[j];
                float b1 = bw[15-j]; int b2 = bidx[15-j];
                bool lt = (a1 < b1) || (a1 == b1 && a2 < b2);
                cv[j] = lt ? a1 : b1; ci[j] = lt ? a2 : b2;
            }
            #pragma unroll
            for (int gap = 8; gap >= 1; gap >>= 1) {
                #pragma unroll
                for (int i = 0; i < 16; ++i) {
                    if ((i & gap) == 0) {
                        const int k2 = i + gap;
                        bool le = (cv[i] < cv[k2]) || (cv[i] == cv[k2] && ci[i] < ci[k2]);
                        float tv = cv[i], tw = cv[k2]; int ti = ci[i], tj = ci[k2];
                        cv[i]  = le ? tv : tw; ci[i]  = le ? ti : tj;
                        cv[k2] = le ? tw : tv; ci[k2] = le ? tj : ti;
                    }
                }
            }
            #pragma unroll
            for (int j = 0; j < 16; ++j) { av[j] = cv[j]; ai[j] = ci[j]; }
        }
        int* orow = &idx_out[((size_t)b*NPTS + n0 + q)*KNBR];
        #pragma unroll
        for (int j = 0; j < 16; ++j) orow[j] = ai[j];
    }
}

// ===========================================================================
// K1: top/phi/psi/alpha.  LDS = sX(34.8K) + sW(32K) => 2 blocks/CU.
// ===========================================================================
__global__ __launch_bounds__(256, 2)
void top_proj_kernel(const float* __restrict__ x,
                     const float* __restrict__ Wt_, const float* __restrict__ bt_,
                     const float* __restrict__ st_, const float* __restrict__ tt_,
                     const float* __restrict__ Wph, const float* __restrict__ bph,
                     const float* __restrict__ Wps, const float* __restrict__ bps,
                     const float* __restrict__ Wal, const float* __restrict__ bal,
                     float* __restrict__ phi, float* __restrict__ psi, float* __restrict__ alp) {
    __shared__ float sX[128*SA];
    __shared__ float sW[64*128];
    const int t = threadIdx.x, tx = t & 15, ty = t >> 4;
    const int r0 = tx*4, c0 = ty*8;
    const int b = blockIdx.y, n0 = blockIdx.x*64;
    #pragma unroll
    for (int rr = 0; rr < 8; ++rr) {
        const int k = rr*16 + ty;
        *(float4*)&sX[k*SA + r0] = *(const float4*)&x[((size_t)b*CDIM + k)*NPTS + n0 + r0];
    }
    stage_wt_half(Wt_, sW, t, 0);
    __syncthreads();
    float topv[4][8] = {};
    gemm64(sX, sW, r0, c0, topv);
    __syncthreads();
    stage_wt_half(Wt_, sW, t, 64);
    __syncthreads();
    gemm64(sX + 64*SA, sW, r0, c0, topv);
    epi_bn<false>(topv, bt_, st_, tt_, c0);
    __syncthreads();                 // all reads of sX done
    write_colmajor(sX, r0, c0, topv);
    stage_wt_half(Wph, sW, t, 0);
    __syncthreads();
    {
        float a2[4][8] = {};
        gemm64(sX, sW, r0, c0, a2);
        __syncthreads(); stage_wt_half(Wph, sW, t, 64); __syncthreads();
        gemm64(sX + 64*SA, sW, r0, c0, a2);
        epi_bias(a2, bph, c0); store_rows(phi, b, n0, r0, c0, a2);
    }
    __syncthreads(); stage_wt_half(Wps, sW, t, 0); __syncthreads();
    {
        float a2[4][8] = {};
        gemm64(sX, sW, r0, c0, a2);
        __syncthreads(); stage_wt_half(Wps, sW, t, 64); __syncthreads();
        gemm64(sX + 64*SA, sW, r0, c0, a2);
        epi_bias(a2, bps, c0); store_rows(psi, b, n0, r0, c0, a2);
    }
    __syncthreads(); stage_wt_half(Wal, sW, t, 0); __syncthreads();
    {
        float a2[4][8] = {};
        gemm64(sX, sW, r0, c0, a2);
        __syncthreads(); stage_wt_half(Wal, sW, t, 64); __syncthreads();
        gemm64(sX + 64*SA, sW, r0, c0, a2);
        epi_bias(a2, bal, c0); store_rows(alp, b, n0, r0, c0, a2);
    }
}

// ===========================================================================
// K2: fused attention.  LDS = sA(34.8K) + sW(32K) + misc(4.7K) = ~71 KB
//     => 2 blocks/CU.  sA is ping-ponged: h -> g0 -> g1 (barrier-protected).
// ===========================================================================
__global__ __launch_bounds__(256, 2)
void pt_attn_kernel(const float* __restrict__ p,
                    const float* __restrict__ phi, const float* __restrict__ psi,
                    const float* __restrict__ alp, const int* __restrict__ idx,
                    const float* __restrict__ W_d1, const float* __restrict__ b_d1,
                    const float* __restrict__ W_d2, const float* __restrict__ b_d2,
                    const float* __restrict__ W_g1, const float* __restrict__ b_g1,
                    const float* __restrict__ W_g2, const float* __restrict__ b_g2,
                    const float* __restrict__ s_d1, const float* __restrict__ t_d1,
                    const float* __restrict__ s_d2, const float* __restrict__ t_d2,
                    const float* __restrict__ s_g1, const float* __restrict__ t_g1,
                    const float* __restrict__ s_g2, const float* __restrict__ t_g2,
                    float* __restrict__ yT) {
    __shared__ float sA[128*SA];
    __shared__ float sW[64*128];
    __shared__ float sWd1[3*128];
    __shared__ float sRel[3*SA];
    __shared__ float sPhi[4*132];
    __shared__ int   sIdx[64];
    const int t = threadIdx.x, tx = t & 15, ty = t >> 4;
    const int r0 = tx*4, c0 = ty*8;
    const int b = blockIdx.y, n0 = blockIdx.x*4;

    // -- P1: small staging + W_d2 half0 --
    if (t < 64) sIdx[t] = idx[((size_t)b*NPTS + n0 + (t >> 4))*KNBR + (t & 15)];
    if (t < 128) {
        const int pt_ = t >> 5, cq = t & 31;
        *(float4*)&sPhi[pt_*132 + cq*4] = *(const float4*)&phi[((size_t)b*NPTS + n0 + pt_)*CDIM + cq*4];
    }
    if (t >= 128) {
        const int c = t - 128;
        #pragma unroll
        for (int j = 0; j < 3; ++j) sWd1[j*128 + c] = W_d1[c*3 + j];
    }
    stage_wt_half(W_d2, sW, t, 0);
    __syncthreads();
    // -- P1b: rel (needs sIdx) --
    if (t < 192) {
        const int j = t / 64, r = t % 64;
        const float pq = p[((size_t)b*3 + j)*NPTS + n0 + (r >> 4)];
        const float pn = p[((size_t)b*3 + j)*NPTS + sIdx[r]];
        sRel[j*SA + r] = pq - pn;
    }
    __syncthreads();
    // -- S2: h = relu(bn_d1(Wd1 rel + b)) -> sA --
    {
        float acc[4][8] = {};
        #pragma unroll
        for (int k = 0; k < 3; ++k) {
            float4 a = *(const float4*)&sRel[k*SA + r0];
            float bv8[8]; load8(&sWd1[k*128], c0, bv8);
            const float av[4] = {a.x, a.y, a.z, a.w};
            #pragma unroll
            for (int i = 0; i < 4; ++i)
                #pragma unroll
                for (int j = 0; j < 8; ++j) acc[i][j] = fmaf(av[i], bv8[j], acc[i][j]);
        }
        epi_bn<true>(acc, b_d1, s_d1, t_d1, c0);
        write_colmajor(sA, r0, c0, acc);
    }
    __syncthreads();
    // -- S3: delta = bn_d2(Wd2 h + b), K-split --
    float dl[4][8] = {};
    gemm64(sA, sW, r0, c0, dl);
    __syncthreads();
    stage_wt_half(W_d2, sW, t, 64);
    __syncthreads();
    gemm64(sA + 64*SA, sW, r0, c0, dl);
    epi_bn<false>(dl, b_d2, s_d2, t_d2, c0);
    __syncthreads();                  // all reads of h done
    // -- P4: g0 = phi - psi_n + delta -> sA (over h); stage W_g1 half0 --
    {
        const int pt_ = tx >> 2;
        float ph[8]; load8(&sPhi[pt_*132], c0, ph);
        float g0[4][8];
        #pragma unroll
        for (int i = 0; i < 4; ++i) {
            const int jn = sIdx[r0 + i];
            float ps[8]; load8(&psi[((size_t)b*NPTS + jn)*CDIM], c0, ps);
            #pragma unroll
            for (int j = 0; j < 8; ++j) g0[i][j] = ph[j] - ps[j] + dl[i][j];
        }
        write_colmajor(sA, r0, c0, g0);
        stage_wt_half(W_g1, sW, t, 0);
    }
    __syncthreads();
    // -- S5: g1 = relu(bn_g1(Wg1 g0 + b)), K-split --
    float g1[4][8] = {};
    gemm64(sA, sW, r0, c0, g1);
    __syncthreads();
    stage_wt_half(W_g1, sW, t, 64);
    __syncthreads();
    gemm64(sA + 64*SA, sW, r0, c0, g1);
    epi_bn<true>(g1, b_g1, s_g1, t_g1, c0);
    __syncthreads();                  // all reads of g0 done
    // -- P6: g1 -> sA (over g0); stage W_g2 half0 --
    write_colmajor(sA, r0, c0, g1);
    stage_wt_half(W_g2, sW, t, 0);
    __syncthreads();
    // -- S6: g2 = bn_g2(Wg2 g1 + b), K-split --
    float g2[4][8] = {};
    gemm64(sA, sW, r0, c0, g2);
    __syncthreads();
    stage_wt_half(W_g2, sW, t, 64);
    __syncthreads();
    gemm64(sA + 64*SA, sW, r0, c0, g2);
    epi_bn<false>(g2, b_g2, s_g2, t_g2, c0);
    // -- softmax over 16 neighbors (4 in-thread rows x lanes tx^1, tx^2) --
    float den[8];
    #pragma unroll
    for (int j = 0; j < 8; ++j) {
        float m_ = fmaxf(fmaxf(g2[0][j], g2[1][j]), fmaxf(g2[2][j], g2[3][j]));
        m_ = fmaxf(m_, __shfl_xor(m_, 1));
        m_ = fmaxf(m_, __shfl_xor(m_, 2));
        float s_ = 0.f;
        #pragma unroll
        for (int i = 0; i < 4; ++i) { g2[i][j] = __expf(g2[i][j] - m_); s_ += g2[i][j]; }
        s_ += __shfl_xor(s_, 1);
        s_ += __shfl_xor(s_, 2);
        den[j] = s_;
    }
    // -- y = sum_k attn * (alpha_n + delta) --
    float ya[8] = {};
    #pragma unroll
    for (int i = 0; i < 4; ++i) {
        const int jn = sIdx[r0 + i];
        float al[8]; load8(&alp[((size_t)b*NPTS + jn)*CDIM], c0, al);
        #pragma unroll
        for (int j = 0; j < 8; ++j) ya[j] = fmaf(g2[i][j], al[j] + dl[i][j], ya[j]);
    }
    #pragma unroll
    for (int j = 0; j < 8; ++j) {
        ya[j] += __shfl_xor(ya[j], 1);
        ya[j] += __shfl_xor(ya[j], 2);
    }
    if ((tx & 3) == 0) {
        const int pt_ = tx >> 2;
        #pragma unroll
        for (int j = 0; j < 8; ++j)
            yT[((size_t)b*CDIM + c0 + j)*NPTS + n0 + pt_] = ya[j] / den[j];
    }
}

// ===========================================================================
// K3: out = bn_down(Wdown y + b) + x.  LDS = sY + sW(32K) => 2 blocks/CU.
// ===========================================================================
__global__ __launch_bounds__(256, 2)
void down_kernel(const float* __restrict__ yT, const float* __restrict__ x,
                 const float* __restrict__ Wd, const float* __restrict__ bd,
                 const float* __restrict__ sd, const float* __restrict__ td,
                 float* __restrict__ out) {
    __shared__ float sY[128*SA];
    __shared__ float sW[64*128];
    const int t = threadIdx.x, tx = t & 15, ty = t >> 4;
    const int r0 = tx*4, c0 = ty*8;
    const int b = blockIdx.y, n0 = blockIdx.x*64;
    #pragma unroll
    for (int rr = 0; rr < 8; ++rr) {
        const int k = rr*16 + ty;
        *(float4*)&sY[k*SA + r0] = *(const float4*)&yT[((size_t)b*CDIM + k)*NPTS + n0 + r0];
    }
    stage_wt_half(Wd, sW, t, 0);
    __syncthreads();
    float acc[4][8] = {};
    gemm64(sY, sW, r0, c0, acc);
    __syncthreads();
    stage_wt_half(Wd, sW, t, 64);
    __syncthreads();
    gemm64(sY + 64*SA, sW, r0, c0, acc);
    epi_bn<false>(acc, bd, sd, td, c0);
    #pragma unroll
    for (int j = 0; j < 8; ++j) {
        const float* xrow = &x[((size_t)b*CDIM + c0 + j)*NPTS + n0 + r0];
        float4 res = *(const float4*)xrow;
        float4 o = make_float4(acc[0][j] + res.x, acc[1][j] + res.y,
                               acc[2][j] + res.z, acc[3][j] + res.w);
        *(float4*)&out[((size_t)b*CDIM + c0 + j)*NPTS + n0 + r0] = o;
    }
}

// ===========================================================================
extern "C" void kernel_launch(void* const* d_in, const int* in_sizes, int n_in,
                              void* d_out, int out_size, void* d_ws, size_t ws_size,
                              hipStream_t stream) {
    const float* p    = (const float*)d_in[0];
    const float* x    = (const float*)d_in[1];
    const float* Wtop = (const float*)d_in[2];  const float* btop = (const float*)d_in[3];
    const float* Wphi = (const float*)d_in[4];  const float* bphi = (const float*)d_in[5];
    const float* Wpsi = (const float*)d_in[6];  const float* bpsi = (const float*)d_in[7];
    const float* Wal  = (const float*)d_in[8];  const float* bal  = (const float*)d_in[9];
    const float* Wd1  = (const float*)d_in[10]; const float* bd1  = (const float*)d_in[11];
    const float* Wd2  = (const float*)d_in[12]; const float* bd2  = (const float*)d_in[13];
    const float* Wg1  = (const float*)d_in[14]; const float* bg1  = (const float*)d_in[15];
    const float* Wg2  = (const float*)d_in[16]; const float* bg2  = (const float*)d_in[17];
    const float* Wdn  = (const float*)d_in[18]; const float* bdn  = (const float*)d_in[19];
    const float* stop = (const float*)d_in[20]; const float* ttop = (const float*)d_in[21];
    const float* sd1  = (const float*)d_in[22]; const float* td1  = (const float*)d_in[23];
    const float* sd2  = (const float*)d_in[24]; const float* td2  = (const float*)d_in[25];
    const float* sg1  = (const float*)d_in[26]; const float* tg1  = (const float*)d_in[27];
    const float* sg2  = (const float*)d_in[28]; const float* tg2  = (const float*)d_in[29];
    const float* sdn  = (const float*)d_in[30]; const float* tdn  = (const float*)d_in[31];

    char* ws = (char*)d_ws;
    int*   idx = (int*)ws;
    float* phi = (float*)(ws + (1 << 20));
    float* psi = phi + (size_t)BATCH*NPTS*CDIM;
    float* alp = psi + (size_t)BATCH*NPTS*CDIM;
    float* yT  = alp + (size_t)BATCH*NPTS*CDIM;

    dim3 gk(NPTS/64, BATCH);
    knn_kernel<<<gk, 512, 0, stream>>>(p, idx);
    dim3 g1(NPTS/64, BATCH);
    top_proj_kernel<<<g1, 256, 0, stream>>>(x, Wtop, btop, stop, ttop,
                                            Wphi, bphi, Wpsi, bpsi, Wal, bal,
                                            phi, psi, alp);
    dim3 g2(NPTS/4, BATCH);
    pt_attn_kernel<<<g2, 256, 0, stream>>>(p, phi, psi, alp, idx,
                                           Wd1, bd1, Wd2, bd2, Wg1, bg1, Wg2, bg2,
                                           sd1, td1, sd2, td2, sg1, tg1, sg2, tg2, yT);
    dim3 g3(NPTS/64, BATCH);
    down_kernel<<<g3, 256, 0, stream>>>(yT, x, Wdn, bdn, sdn, tdn, (float*)d_out);
}